// Round 7
// baseline (79.378 us; speedup 1.0000x reference)
//
#include <hip/hip_runtime.h>
#include <stdint.h>

#define B_   8
#define C_   128
#define N_   8192
#define K_   16
#define O_   128
#define NP   65536                      // B_*N_ total points
#define PL32 ((size_t)NP * 32)          // elems per 32-channel plane (4 MB)
#define TPF  32                         // points/block in fused fallback

typedef __attribute__((ext_vector_type(8))) short short8;
typedef __attribute__((ext_vector_type(4))) float f32x4;
typedef __attribute__((ext_vector_type(4))) uint32_t u32x4;

__device__ __forceinline__ unsigned short f2bf(float f) {
    union { float f; uint32_t u; } v; v.f = f;
    uint32_t u = v.u;
    return (unsigned short)((u + 0x7FFFu + ((u >> 16) & 1u)) >> 16);  // RNE
}
// Orderable-u16 map for bf16 (monotone bijection; unsigned cmp == float cmp)
__device__ __forceinline__ uint32_t fwdmap(uint32_t u) {
    uint32_t s  = u & 0x80008000u;
    uint32_t xm = s - (s >> 15) + 0x80008000u;
    return u ^ xm;
}
__device__ __forceinline__ uint32_t invmap(uint32_t v) {
    uint32_t s  = (~v) & 0x80008000u;
    uint32_t xm = s - (s >> 15) + 0x80008000u;
    return v ^ xm;
}
__device__ __forceinline__ uint32_t pkmax(uint32_t a, uint32_t b) {
    uint32_t d;
    asm("v_pk_max_u16 %0, %1, %2" : "=v"(d) : "v"(a), "v"(b));
    return d;
}
__device__ __forceinline__ uint4 pkmax4(uint4 a, uint4 b) {
    return make_uint4(pkmax(a.x, b.x), pkmax(a.y, b.y),
                      pkmax(a.z, b.z), pkmax(a.w, b.w));
}

// ---------------- BIG PATH (ws >= 32MB+32KB): 3 kernels ----------------

// x (B,C,N) f32 -> 4 channel-planes xt[g][NP][32] orderable-u16.
// Extra block (blk==1024) converts W -> bf16.
__global__ __launch_bounds__(256) void k_transpose_pl(const float* __restrict__ x,
                                                      unsigned short* __restrict__ xt,
                                                      const float* __restrict__ Wp,
                                                      unsigned short* __restrict__ Wbf) {
    int blk = blockIdx.x;
    if (blk == 1024) {
        int t = threadIdx.x;
        #pragma unroll
        for (int i = 0; i < 32; ++i) {
            int e = t + i * 256;
            float2 w2 = ((const float2*)Wp)[e];
            ((uint32_t*)Wbf)[e] = (uint32_t)f2bf(w2.x) | ((uint32_t)f2bf(w2.y) << 16);
        }
        return;
    }
    __shared__ uint32_t lds[64 * 66];
    int t    = threadIdx.x;
    int lane = t & 63;
    int wv   = t >> 6;
    int b    = blk >> 7;
    int n0   = (blk & 127) * 64;

    const float* xb = x + (size_t)b * C_ * N_ + n0 + lane;
    #pragma unroll
    for (int j = 0; j < 16; ++j) {
        int c2 = wv * 16 + j;
        float f0 = xb[(size_t)(2 * c2) * N_];
        float f1 = xb[(size_t)(2 * c2 + 1) * N_];
        uint32_t pk = (uint32_t)f2bf(f0) | ((uint32_t)f2bf(f1) << 16);
        lds[c2 * 66 + lane] = fwdmap(pk);
    }
    __syncthreads();

    int rr = lane >> 2;    // row 0..15 in wave's strip
    int ch = lane & 3;     // 16B chunk of 64B plane-row
    size_t rowb = (size_t)(b * N_ + n0);
    #pragma unroll
    for (int pl = 0; pl < 4; ++pl) {
        int r = wv * 16 + rr;
        uint32_t u0 = lds[(pl * 16 + ch * 4 + 0) * 66 + r];
        uint32_t u1 = lds[(pl * 16 + ch * 4 + 1) * 66 + r];
        uint32_t u2 = lds[(pl * 16 + ch * 4 + 2) * 66 + r];
        uint32_t u3 = lds[(pl * 16 + ch * 4 + 3) * 66 + r];
        *(uint4*)(xt + (size_t)pl * PL32 + (rowb + r) * 32 + ch * 8) =
            make_uint4(u0, u1, u2, u3);
    }
}

// Gather+max, channel-sharded by XCD: block -> XCD x = blk&7 (round-robin
// dispatch), group g = x&3 (its 4MB plane stays L2-resident), half h = x>>2.
// 128 points/block; lane = (pt 0..15, 16B chunk 0..3 of the 64B slice);
// 16 independent loads/pt then pkmax tree. agg written as planes (dense nt).
__global__ __launch_bounds__(256, 4) void k_gather(const unsigned short* __restrict__ xt,
                                                   const int* __restrict__ idx,
                                                   unsigned short* __restrict__ agg4) {
    __shared__ int idxs[K_ * 128];   // transposed [k][p] -> conflict-free reads
    int t    = threadIdx.x;
    int lane = t & 63;
    int wv   = t >> 6;
    int blk  = blockIdx.x;           // 2048
    int xcd  = blk & 7;
    int g    = xcd & 3;
    int h    = xcd >> 2;
    int tile = blk >> 3;             // 0..255
    int p0   = h * 32768 + tile * 128;

    const int* ip = idx + (size_t)p0 * K_;
    #pragma unroll
    for (int i = 0; i < 8; ++i) {
        int e = t + i * 256;
        int pl_ = e & 127, k = e >> 7;
        idxs[k * 128 + pl_] = __builtin_nontemporal_load(ip + pl_ * K_ + k);
    }
    __syncthreads();

    const unsigned short* plane  = xt   + (size_t)g * PL32;
    unsigned short*       aplane = agg4 + (size_t)g * PL32;
    int pt = lane >> 2;    // point within group of 16
    int c4 = lane & 3;     // 16B chunk of 64B slice
    #pragma unroll
    for (int pass = 0; pass < 2; ++pass) {
        int pl_ = wv * 32 + pass * 16 + pt;     // local point 0..127
        const unsigned short* basep = plane + c4 * 8;
        uint4 d[16];
        #pragma unroll
        for (int k = 0; k < 16; ++k) {
            int q = idxs[k * 128 + pl_];
            d[k] = *(const uint4*)(basep + (size_t)q * 32);
        }
        #pragma unroll
        for (int s = 8; s >= 1; s >>= 1)
            #pragma unroll
            for (int k = 0; k < s; ++k)
                d[k] = pkmax4(d[k], d[k + s]);
        u32x4 v;
        v[0] = invmap(d[0].x); v[1] = invmap(d[0].y);
        v[2] = invmap(d[0].z); v[3] = invmap(d[0].w);
        __builtin_nontemporal_store(v, (u32x4*)(aplane + (size_t)(p0 + pl_) * 32 + c4 * 8));
    }
}

// GEMM: 64 points/block (grid 1024). agg planes + Wbf -> out, bias+ReLU.
// (Round-6 bug: pt2 only covered 32 of the 64 points -> half the output
//  stayed zero. Fixed: pt2 < 4.)
__global__ __launch_bounds__(256) void k_gemm(const unsigned short* __restrict__ agg4,
                                              const unsigned short* __restrict__ Wbf,
                                              const float* __restrict__ bp,
                                              float* __restrict__ out) {
    int t    = threadIdx.x;
    int lane = t & 63;
    int wv   = t >> 6;
    int blk  = blockIdx.x;          // 1024
    int p0   = blk * 64;
    int b    = p0 >> 13;
    int n0   = p0 & (N_ - 1);
    int r16  = lane & 15;
    int h    = lane >> 4;
    int wo   = wv * 32;
    const size_t ob = (size_t)b * O_ * N_ + n0;

    #pragma unroll
    for (int ot2 = 0; ot2 < 2; ++ot2) {
        short8 af[4];
        #pragma unroll
        for (int kk = 0; kk < 4; ++kk)
            af[kk] = *(const short8*)(Wbf + (size_t)(wo + ot2 * 16 + r16) * C_ + kk * 32 + h * 8);
        float4 bv = *(const float4*)(bp + wo + ot2 * 16 + h * 4);
        int orow = wo + ot2 * 16 + h * 4;
        #pragma unroll
        for (int pt2 = 0; pt2 < 4; ++pt2) {
            short8 bfr[4];
            #pragma unroll
            for (int kk = 0; kk < 4; ++kk)   // plane kk holds channels kk*32..+31
                bfr[kk] = *(const short8*)(agg4 + (size_t)kk * PL32
                                           + (size_t)(p0 + pt2 * 16 + r16) * 32 + h * 8);
            f32x4 acc = {0.f, 0.f, 0.f, 0.f};
            #pragma unroll
            for (int kk = 0; kk < 4; ++kk)
                acc = __builtin_amdgcn_mfma_f32_16x16x32_bf16(af[kk], bfr[kk], acc, 0, 0, 0);
            float* op = out + ob + (size_t)orow * N_ + pt2 * 16 + r16;
            __builtin_nontemporal_store(fmaxf(acc[0] + bv.x, 0.f), op);
            __builtin_nontemporal_store(fmaxf(acc[1] + bv.y, 0.f), op + (size_t)N_);
            __builtin_nontemporal_store(fmaxf(acc[2] + bv.z, 0.f), op + (size_t)2 * N_);
            __builtin_nontemporal_store(fmaxf(acc[3] + bv.w, 0.f), op + (size_t)3 * N_);
        }
    }
}

// ---------------- FALLBACK PATH (round-5, ws >= 16MB+32KB) ----------------

template<bool PREW>
__global__ __launch_bounds__(256) void k_transpose_flat(const float* __restrict__ x,
                                                        unsigned short* __restrict__ xt,
                                                        const float* __restrict__ Wp,
                                                        unsigned short* __restrict__ Wbf) {
    int blk = blockIdx.x;
    if (PREW && blk == 1024) {
        int t = threadIdx.x;
        #pragma unroll
        for (int i = 0; i < 32; ++i) {
            int e = t + i * 256;
            float2 w2 = ((const float2*)Wp)[e];
            ((uint32_t*)Wbf)[e] = (uint32_t)f2bf(w2.x) | ((uint32_t)f2bf(w2.y) << 16);
        }
        return;
    }
    __shared__ uint32_t lds[64 * 66];
    int t    = threadIdx.x;
    int lane = t & 63;
    int wv   = t >> 6;
    int b    = blk >> 7;
    int n0   = (blk & 127) * 64;

    const float* xb = x + (size_t)b * C_ * N_ + n0 + lane;
    #pragma unroll
    for (int j = 0; j < 16; ++j) {
        int c2 = wv * 16 + j;
        float f0 = xb[(size_t)(2 * c2) * N_];
        float f1 = xb[(size_t)(2 * c2 + 1) * N_];
        uint32_t pk = (uint32_t)f2bf(f0) | ((uint32_t)f2bf(f1) << 16);
        lds[c2 * 66 + lane] = fwdmap(pk);
    }
    __syncthreads();
    int rl = lane >> 4;
    int ch = lane & 15;
    #pragma unroll
    for (int it = 0; it < 4; ++it) {
        int r = it * 16 + wv * 4 + rl;
        uint32_t u0 = lds[(ch * 4 + 0) * 66 + r];
        uint32_t u1 = lds[(ch * 4 + 1) * 66 + r];
        uint32_t u2 = lds[(ch * 4 + 2) * 66 + r];
        uint32_t u3 = lds[(ch * 4 + 3) * 66 + r];
        *(uint4*)(xt + ((size_t)(b * N_ + n0 + r)) * C_ + ch * 8) =
            make_uint4(u0, u1, u2, u3);
    }
}

template<bool PREW>
__global__ __launch_bounds__(256, 4) void k_fused(const unsigned short* __restrict__ xt,
                                                  const int* __restrict__ idx,
                                                  const float* __restrict__ Wp,
                                                  const unsigned short* __restrict__ Wbf,
                                                  const float* __restrict__ bp,
                                                  float* __restrict__ out) {
    __shared__ __align__(16) unsigned short agg[TPF * 136];
    __shared__ int idxs[TPF * K_];

    int t    = threadIdx.x;
    int lane = t & 63;
    int wv   = t >> 6;
    int blk  = blockIdx.x;
    int b    = blk >> 8;
    int n0   = (blk & 255) * TPF;
    size_t pbase = (size_t)b * N_ + n0;

    const int* ip = idx + pbase * K_;
    idxs[t]       = __builtin_nontemporal_load(ip + t);
    idxs[t + 256] = __builtin_nontemporal_load(ip + t + 256);
    __syncthreads();

    int pt  = lane >> 4;
    int cch = lane & 15;
    #pragma unroll
    for (int i = 0; i < 2; ++i) {
        int p = wv * 8 + i * 4 + pt;
        const int* qq = &idxs[p * K_];
        uint4 d[16];
        #pragma unroll
        for (int k = 0; k < 16; ++k)
            d[k] = *(const uint4*)(xt + (size_t)qq[k] * C_ + cch * 8);
        #pragma unroll
        for (int s = 8; s >= 1; s >>= 1)
            #pragma unroll
            for (int k = 0; k < s; ++k)
                d[k] = pkmax4(d[k], d[k + s]);
        uint4 v = make_uint4(invmap(d[0].x), invmap(d[0].y),
                             invmap(d[0].z), invmap(d[0].w));
        *(uint4*)&agg[p * 136 + cch * 8] = v;
    }
    __syncthreads();

    int r16 = lane & 15;
    int h   = lane >> 4;
    int wo  = wv * 32;
    const size_t ob = (size_t)b * O_ * N_ + n0;

    #pragma unroll
    for (int ot2 = 0; ot2 < 2; ++ot2) {
        short8 af[4];
        if (PREW) {
            #pragma unroll
            for (int kk = 0; kk < 4; ++kk)
                af[kk] = *(const short8*)(Wbf + (size_t)(wo + ot2 * 16 + r16) * C_ + kk * 32 + h * 8);
        } else {
            #pragma unroll
            for (int kk = 0; kk < 4; ++kk) {
                const float* wr = Wp + (size_t)(wo + ot2 * 16 + r16) * C_ + kk * 32 + h * 8;
                float4 a0 = *(const float4*)wr;
                float4 a1 = *(const float4*)(wr + 4);
                short8 s;
                s[0] = (short)f2bf(a0.x); s[1] = (short)f2bf(a0.y);
                s[2] = (short)f2bf(a0.z); s[3] = (short)f2bf(a0.w);
                s[4] = (short)f2bf(a1.x); s[5] = (short)f2bf(a1.y);
                s[6] = (short)f2bf(a1.z); s[7] = (short)f2bf(a1.w);
                af[kk] = s;
            }
        }
        float4 bv = *(const float4*)(bp + wo + ot2 * 16 + h * 4);
        int orow = wo + ot2 * 16 + h * 4;
        #pragma unroll
        for (int pt2 = 0; pt2 < 2; ++pt2) {
            short8 bfr[4];
            #pragma unroll
            for (int kk = 0; kk < 4; ++kk)
                bfr[kk] = *(const short8*)&agg[(pt2 * 16 + r16) * 136 + kk * 32 + h * 8];
            f32x4 acc = {0.f, 0.f, 0.f, 0.f};
            #pragma unroll
            for (int kk = 0; kk < 4; ++kk)
                acc = __builtin_amdgcn_mfma_f32_16x16x32_bf16(af[kk], bfr[kk], acc, 0, 0, 0);
            float* op = out + ob + (size_t)orow * N_ + pt2 * 16 + r16;
            __builtin_nontemporal_store(fmaxf(acc[0] + bv.x, 0.f), op);
            __builtin_nontemporal_store(fmaxf(acc[1] + bv.y, 0.f), op + (size_t)N_);
            __builtin_nontemporal_store(fmaxf(acc[2] + bv.z, 0.f), op + (size_t)2 * N_);
            __builtin_nontemporal_store(fmaxf(acc[3] + bv.w, 0.f), op + (size_t)3 * N_);
        }
    }
}

extern "C" void kernel_launch(void* const* d_in, const int* in_sizes, int n_in,
                              void* d_out, int out_size, void* d_ws, size_t ws_size,
                              hipStream_t stream) {
    (void)in_sizes; (void)n_in; (void)out_size;
    const float* x    = (const float*)d_in[0];
    const int*   idx  = (const int*)d_in[1];
    const float* W    = (const float*)d_in[2];
    const float* bias = (const float*)d_in[3];
    float* out = (float*)d_out;

    const size_t PLB = (size_t)4 * PL32 * 2;    // 16 MB of xt planes
    const size_t WB  = (size_t)O_ * C_ * 2;     // 32 KB Wbf

    if (ws_size >= 2 * PLB + WB) {
        unsigned short* xt   = (unsigned short*)d_ws;
        unsigned short* agg4 = (unsigned short*)((char*)d_ws + PLB);
        unsigned short* wbf  = (unsigned short*)((char*)d_ws + 2 * PLB);
        hipLaunchKernelGGL(k_transpose_pl, dim3(1025), dim3(256), 0, stream, x, xt, W, wbf);
        hipLaunchKernelGGL(k_gather,       dim3(2048), dim3(256), 0, stream, xt, idx, agg4);
        hipLaunchKernelGGL(k_gemm,         dim3(1024), dim3(256), 0, stream, agg4, wbf, bias, out);
    } else if (ws_size >= PLB + WB) {
        unsigned short* xt  = (unsigned short*)d_ws;
        unsigned short* wbf = (unsigned short*)((char*)d_ws + PLB);
        hipLaunchKernelGGL(k_transpose_flat<true>, dim3(1025), dim3(256), 0, stream, x, xt, W, wbf);
        hipLaunchKernelGGL(k_fused<true>,          dim3(2048), dim3(256), 0, stream, xt, idx, W, wbf, bias, out);
    } else {
        unsigned short* xt = (unsigned short*)d_ws;
        hipLaunchKernelGGL(k_transpose_flat<false>, dim3(1024), dim3(256), 0, stream, x, xt, W, nullptr);
        hipLaunchKernelGGL(k_fused<false>,          dim3(2048), dim3(256), 0, stream, xt, idx, W, nullptr, bias, out);
    }
}

// Round 8
// 50.868 us; speedup vs baseline: 1.5605x; 1.5605x over previous
//
#include <hip/hip_runtime.h>
#include <stdint.h>

#define B_  8
#define C_  128
#define N_  8192
#define K_  16
#define O_  128
#define TPF 32     // points per k_fused block -> grid 2048

typedef __attribute__((ext_vector_type(8))) short short8;
typedef __attribute__((ext_vector_type(4))) float f32x4;

__device__ __forceinline__ unsigned short f2bf(float f) {
    union { float f; uint32_t u; } v; v.f = f;
    uint32_t u = v.u;
    return (unsigned short)((u + 0x7FFFu + ((u >> 16) & 1u)) >> 16);  // RNE
}
// Orderable-u16 map for bf16 (monotone bijection; unsigned cmp == float cmp)
__device__ __forceinline__ uint32_t fwdmap(uint32_t u) {
    uint32_t s  = u & 0x80008000u;
    uint32_t xm = s - (s >> 15) + 0x80008000u;
    return u ^ xm;
}
__device__ __forceinline__ uint32_t invmap(uint32_t v) {
    uint32_t s  = (~v) & 0x80008000u;
    uint32_t xm = s - (s >> 15) + 0x80008000u;
    return v ^ xm;
}
__device__ __forceinline__ uint32_t pkmax(uint32_t a, uint32_t b) {
    uint32_t d;
    asm("v_pk_max_u16 %0, %1, %2" : "=v"(d) : "v"(a), "v"(b));
    return d;
}
__device__ __forceinline__ uint4 pkmax4(uint4 a, uint4 b) {
    return make_uint4(pkmax(a.x, b.x), pkmax(a.y, b.y),
                      pkmax(a.z, b.z), pkmax(a.w, b.w));
}

// Kernel 1: x (B,C,N) f32 -> xt (B*N, C) orderable-u16 row-major (256B rows).
// Extra block (blk==1024) pre-converts W to bf16.
template<bool PREW>
__global__ __launch_bounds__(256) void k_transpose(const float* __restrict__ x,
                                                   unsigned short* __restrict__ xt,
                                                   const float* __restrict__ Wp,
                                                   unsigned short* __restrict__ Wbf) {
    int blk = blockIdx.x;
    if (PREW && blk == 1024) {
        int t = threadIdx.x;
        #pragma unroll
        for (int i = 0; i < 32; ++i) {
            int e = t + i * 256;
            float2 w2 = ((const float2*)Wp)[e];
            ((uint32_t*)Wbf)[e] = (uint32_t)f2bf(w2.x) | ((uint32_t)f2bf(w2.y) << 16);
        }
        return;
    }
    __shared__ uint32_t lds[64 * 66];
    int t    = threadIdx.x;
    int lane = t & 63;
    int wv   = t >> 6;
    int b    = blk >> 7;
    int n0   = (blk & 127) * 64;

    const float* xb = x + (size_t)b * C_ * N_ + n0 + lane;
    #pragma unroll
    for (int j = 0; j < 16; ++j) {
        int c2 = wv * 16 + j;
        float f0 = xb[(size_t)(2 * c2) * N_];
        float f1 = xb[(size_t)(2 * c2 + 1) * N_];
        uint32_t pk = (uint32_t)f2bf(f0) | ((uint32_t)f2bf(f1) << 16);
        lds[c2 * 66 + lane] = fwdmap(pk);
    }
    __syncthreads();
    int rl = lane >> 4;
    int ch = lane & 15;
    #pragma unroll
    for (int it = 0; it < 4; ++it) {
        int r = it * 16 + wv * 4 + rl;
        uint32_t u0 = lds[(ch * 4 + 0) * 66 + r];
        uint32_t u1 = lds[(ch * 4 + 1) * 66 + r];
        uint32_t u2 = lds[(ch * 4 + 2) * 66 + r];
        uint32_t u3 = lds[(ch * 4 + 3) * 66 + r];
        *(uint4*)(xt + ((size_t)(b * N_ + n0 + r)) * C_ + ch * 8) =
            make_uint4(u0, u1, u2, u3);
    }
}

// Kernel 2: fused gather+max+GEMM, 32 points/block, grid 2048.
// Gather with FORCED 16-deep MLP: 16 idx LDS reads hoisted, 16 named uint4
// global loads, sched_barrier(0) fences so the compiler cannot serialize the
// batch to save registers (rounds 3/7 showed VGPR 56/32 => MLP 2-3).
template<bool PREW>
__global__ __launch_bounds__(256, 4) void k_fused(const unsigned short* __restrict__ xt,
                                                  const int* __restrict__ idx,
                                                  const float* __restrict__ Wp,
                                                  const unsigned short* __restrict__ Wbf,
                                                  const float* __restrict__ bp,
                                                  float* __restrict__ out) {
    __shared__ __align__(16) unsigned short agg[TPF * 136];
    __shared__ int idxs[TPF * K_];

    int t    = threadIdx.x;
    int lane = t & 63;
    int wv   = t >> 6;
    int blk  = blockIdx.x;
    int b    = blk >> 8;
    int n0   = (blk & 255) * TPF;
    size_t pbase = (size_t)b * N_ + n0;

    const int* ip = idx + pbase * K_;
    idxs[t]       = __builtin_nontemporal_load(ip + t);
    idxs[t + 256] = __builtin_nontemporal_load(ip + t + 256);
    __syncthreads();

    int pt  = lane >> 4;   // point within group of 4
    int cch = lane & 15;   // 16B chunk of 256B row
    const unsigned short* bx = xt + cch * 8;

    #pragma unroll
    for (int i = 0; i < 2; ++i) {
        int p = wv * 8 + i * 4 + pt;
        const int* qq = &idxs[p * K_];
        // --- phase 1: all 16 row indices from LDS ---
        int q0 = qq[0],  q1 = qq[1],  q2 = qq[2],  q3 = qq[3];
        int q4 = qq[4],  q5 = qq[5],  q6 = qq[6],  q7 = qq[7];
        int q8 = qq[8],  q9 = qq[9],  q10 = qq[10], q11 = qq[11];
        int q12 = qq[12], q13 = qq[13], q14 = qq[14], q15 = qq[15];
        __builtin_amdgcn_sched_barrier(0);
        // --- phase 2: 16 independent 16B gathers, all in flight ---
        uint4 d0  = *(const uint4*)(bx + (size_t)q0  * C_);
        uint4 d1  = *(const uint4*)(bx + (size_t)q1  * C_);
        uint4 d2  = *(const uint4*)(bx + (size_t)q2  * C_);
        uint4 d3  = *(const uint4*)(bx + (size_t)q3  * C_);
        uint4 d4  = *(const uint4*)(bx + (size_t)q4  * C_);
        uint4 d5  = *(const uint4*)(bx + (size_t)q5  * C_);
        uint4 d6  = *(const uint4*)(bx + (size_t)q6  * C_);
        uint4 d7  = *(const uint4*)(bx + (size_t)q7  * C_);
        uint4 d8  = *(const uint4*)(bx + (size_t)q8  * C_);
        uint4 d9  = *(const uint4*)(bx + (size_t)q9  * C_);
        uint4 d10 = *(const uint4*)(bx + (size_t)q10 * C_);
        uint4 d11 = *(const uint4*)(bx + (size_t)q11 * C_);
        uint4 d12 = *(const uint4*)(bx + (size_t)q12 * C_);
        uint4 d13 = *(const uint4*)(bx + (size_t)q13 * C_);
        uint4 d14 = *(const uint4*)(bx + (size_t)q14 * C_);
        uint4 d15 = *(const uint4*)(bx + (size_t)q15 * C_);
        __builtin_amdgcn_sched_barrier(0);
        // --- phase 3: depth-4 pkmax tree (waitcnt inserted per-use) ---
        d0 = pkmax4(d0, d8);  d1 = pkmax4(d1, d9);
        d2 = pkmax4(d2, d10); d3 = pkmax4(d3, d11);
        d4 = pkmax4(d4, d12); d5 = pkmax4(d5, d13);
        d6 = pkmax4(d6, d14); d7 = pkmax4(d7, d15);
        d0 = pkmax4(d0, d4);  d1 = pkmax4(d1, d5);
        d2 = pkmax4(d2, d6);  d3 = pkmax4(d3, d7);
        d0 = pkmax4(d0, d2);  d1 = pkmax4(d1, d3);
        d0 = pkmax4(d0, d1);
        uint4 v = make_uint4(invmap(d0.x), invmap(d0.y),
                             invmap(d0.z), invmap(d0.w));
        *(uint4*)&agg[p * 136 + cch * 8] = v;
    }
    __syncthreads();

    // ---- MFMA GEMM: wave computes o in [wo,wo+32) x 32 points ----
    int r16 = lane & 15;
    int h   = lane >> 4;
    int wo  = wv * 32;
    const size_t ob = (size_t)b * O_ * N_ + n0;

    #pragma unroll
    for (int ot2 = 0; ot2 < 2; ++ot2) {
        short8 af[4];
        if (PREW) {
            #pragma unroll
            for (int kk = 0; kk < 4; ++kk)
                af[kk] = *(const short8*)(Wbf + (size_t)(wo + ot2 * 16 + r16) * C_ + kk * 32 + h * 8);
        } else {
            #pragma unroll
            for (int kk = 0; kk < 4; ++kk) {
                const float* wr = Wp + (size_t)(wo + ot2 * 16 + r16) * C_ + kk * 32 + h * 8;
                float4 a0 = *(const float4*)wr;
                float4 a1 = *(const float4*)(wr + 4);
                short8 s;
                s[0] = (short)f2bf(a0.x); s[1] = (short)f2bf(a0.y);
                s[2] = (short)f2bf(a0.z); s[3] = (short)f2bf(a0.w);
                s[4] = (short)f2bf(a1.x); s[5] = (short)f2bf(a1.y);
                s[6] = (short)f2bf(a1.z); s[7] = (short)f2bf(a1.w);
                af[kk] = s;
            }
        }
        float4 bv = *(const float4*)(bp + wo + ot2 * 16 + h * 4);
        int orow = wo + ot2 * 16 + h * 4;
        #pragma unroll
        for (int pt2 = 0; pt2 < 2; ++pt2) {
            short8 bfr[4];
            #pragma unroll
            for (int kk = 0; kk < 4; ++kk)
                bfr[kk] = *(const short8*)&agg[(pt2 * 16 + r16) * 136 + kk * 32 + h * 8];
            f32x4 acc = {0.f, 0.f, 0.f, 0.f};
            #pragma unroll
            for (int kk = 0; kk < 4; ++kk)
                acc = __builtin_amdgcn_mfma_f32_16x16x32_bf16(af[kk], bfr[kk], acc, 0, 0, 0);
            float* op = out + ob + (size_t)orow * N_ + pt2 * 16 + r16;
            __builtin_nontemporal_store(fmaxf(acc[0] + bv.x, 0.f), op);
            __builtin_nontemporal_store(fmaxf(acc[1] + bv.y, 0.f), op + (size_t)N_);
            __builtin_nontemporal_store(fmaxf(acc[2] + bv.z, 0.f), op + (size_t)2 * N_);
            __builtin_nontemporal_store(fmaxf(acc[3] + bv.w, 0.f), op + (size_t)3 * N_);
        }
    }
}

extern "C" void kernel_launch(void* const* d_in, const int* in_sizes, int n_in,
                              void* d_out, int out_size, void* d_ws, size_t ws_size,
                              hipStream_t stream) {
    (void)in_sizes; (void)n_in; (void)out_size;
    const float* x    = (const float*)d_in[0];
    const int*   idx  = (const int*)d_in[1];
    const float* W    = (const float*)d_in[2];
    const float* bias = (const float*)d_in[3];
    float* out = (float*)d_out;

    const size_t XTB = (size_t)B_ * N_ * C_ * 2;    // 16 MB table
    const size_t WB  = (size_t)O_ * C_ * 2;         // 32 KB Wbf
    unsigned short* xt  = (unsigned short*)d_ws;
    unsigned short* wbf = (unsigned short*)((char*)d_ws + XTB);

    if (ws_size >= XTB + WB) {
        hipLaunchKernelGGL(k_transpose<true>, dim3(1025), dim3(256), 0, stream, x, xt, W, wbf);
        hipLaunchKernelGGL(k_fused<true>,     dim3(2048), dim3(256), 0, stream, xt, idx, W, wbf, bias, out);
    } else {
        hipLaunchKernelGGL(k_transpose<false>, dim3(1024), dim3(256), 0, stream, x, xt, W, nullptr);
        hipLaunchKernelGGL(k_fused<false>,     dim3(2048), dim3(256), 0, stream, xt, idx, W, nullptr, bias, out);
    }
}